// Round 8
// baseline (227.364 us; speedup 1.0000x reference)
//
#include <hip/hip_runtime.h>
#include <cstdint>

// B=4, S=2048, D_IN=D_OUT=1024; softmax scale = 1/sqrt(1024) = 0.03125
// exp without max-subtraction is safe (|scores| ~< 3); L = rowsum via atomics;
// 1/L folded into PV epilogue.
//
// R8 structure: 4 kernels.
//   cvt (+zero Out rows>=1024) -> gemm_qkv(Q,K; 16x64) -> gemm_sv (merged
//   scores+V, 1056 blk) -> gemm_pv (split-K 2-way for by>=8, 768 blk).
// Ledger (R6/R7 counters): qk=43.4, sv=54.1, pv<43.4, cvt~15, gaps ~5/launch,
// fixed per-rep harness overhead ~45us. pv's makespan was pinned by 32
// by=15 blocks with 32 k-steps (2x everything else); split-K halves the
// critical path to 16 steps for all blocks. Split halves atomicAdd
// pre-normalized fp32 partials (L is final before pv); shallow rows store
// plainly; cvt zeroes the atomic region (16MB). Flash-fusion permanently
// rejected: d=1024 => K-restream ~1GB through L2/L3.
// History: R2 256^2 8-phase = 84us (reverted); R5 col-64 split = +7us
// (reverted); block-level GEMM structure is the measured m97-style 128x128
// BK=64, 8-chunk XOR LDS swizzle (0 conflicts), global_load_lds, T1 XCD.

typedef __attribute__((ext_vector_type(8))) __bf16 bf16x8;
typedef __attribute__((ext_vector_type(4))) float f32x4;

#define BK 64

__device__ __forceinline__ unsigned short f2bf(float f) {
  union { float f; unsigned u; } v; v.f = f;
  unsigned r = v.u + 0x7fffu + ((v.u >> 16) & 1u);  // RNE
  return (unsigned short)(r >> 16);
}

__device__ __forceinline__ void gload_lds16(const void* g, void* l) {
  __builtin_amdgcn_global_load_lds(
      (const __attribute__((address_space(1))) void*)g,
      (__attribute__((address_space(3))) void*)l, 16, 0, 0);
}

// ---- fused fp32->bf16 conversion (X + weights) + L zero + Out-region zero --
__global__ __launch_bounds__(256)
void cvt_all(const float* __restrict__ X, const float* __restrict__ Wq,
             const float* __restrict__ Wk, const float* __restrict__ Wv,
             unsigned short* __restrict__ Xbf, unsigned short* __restrict__ Wall,
             float* __restrict__ L, float* __restrict__ Out) {
  const int bid = blockIdx.x;
  if (bid >= 11268) {  // 1024 blocks: zero Out rows [1024,2048) per batch
    const int m = bid - 11268;
    const int bz = m >> 8, blk = m & 255;
    float4* p = (float4*)(Out + (size_t)bz * 2097152 + 1048576 + (size_t)blk * 4096);
    #pragma unroll
    for (int u = 0; u < 4; ++u)
      p[threadIdx.x + u * 256] = (float4){0.f, 0.f, 0.f, 0.f};
    return;
  }
  if (bid >= 11264) {  // 4 blocks zero L[4][2048]
    float4* p = (float4*)(L + (size_t)(bid - 11264) * 2048);
    p[threadIdx.x] = (float4){0.f, 0.f, 0.f, 0.f};
    p[threadIdx.x + 256] = (float4){0.f, 0.f, 0.f, 0.f};
    return;
  }
  const float* src;
  unsigned short* dst;
  int i;
  if (bid < 8192) {
    src = X; dst = Xbf; i = bid * 256 + threadIdx.x;
  } else {
    const int m = bid - 8192;
    const int sel = m >> 10;
    src = (sel == 0) ? Wq : (sel == 1) ? Wk : Wv;
    dst = Wall + (size_t)sel * 1048576;
    i = (m & 1023) * 256 + threadIdx.x;
  }
  float4 v = ((const float4*)src)[i];
  ushort4 o;
  o.x = f2bf(v.x); o.y = f2bf(v.y); o.z = f2bf(v.z); o.w = f2bf(v.w);
  ((ushort4*)dst)[i] = o;
}

// -------------------- Q/K GEMM (128x128, BK=64) --------------------
// A = Xbf [8192][1024], B = Wall [3072][1024]; grid (16,64): bx<8 -> Q,
// else K.
__global__ __launch_bounds__(256, 3)
void gemm_qkv(const unsigned short* __restrict__ A,
              const unsigned short* __restrict__ Bm,
              unsigned short* __restrict__ Qb,
              unsigned short* __restrict__ Kb)
{
  // T1: bijective XCD swizzle (1024 % 8 == 0); 8 consecutive by-rows/XCD.
  const int NX = gridDim.x;
  const int lin = blockIdx.y * NX + blockIdx.x;
  const int chunk = (NX * 64) >> 3;
  const int swz = (lin & 7) * chunk + (lin >> 3);
  const int bx = swz % NX, by = swz / NX;

  __shared__ __align__(16) unsigned short As[128 * BK];  // 16 KB
  __shared__ __align__(16) unsigned short Bs[128 * BK];  // 16 KB

  const int tid = threadIdx.x;
  const int wave = tid >> 6, lane = tid & 63;
  const int wr = wave >> 1, wc = wave & 1;
  const int quad = lane >> 4, l16 = lane & 15;

  const unsigned rsub = wave * 8 + (lane >> 3);
  const unsigned csb = (unsigned)(((lane & 7) ^ ((lane >> 3) & 7)) * 16);

  unsigned offA[4], offB[4];
  #pragma unroll
  for (int s = 0; s < 4; ++s) {
    offA[s] = ((unsigned)(by * 128 + s * 32 + rsub) * 1024u) * 2u + csb;
    offB[s] = ((unsigned)(bx * 128 + s * 32 + rsub) * 1024u) * 2u + csb;
  }
  const char* Abase = (const char*)A;
  const char* Bbase = (const char*)Bm;

  f32x4 acc[4][4];
  #pragma unroll
  for (int i = 0; i < 4; ++i)
    #pragma unroll
    for (int j = 0; j < 4; ++j)
      acc[i][j] = (f32x4){0.f, 0.f, 0.f, 0.f};

  const int pq = (quad ^ (l16 & 7)) * 8;
  const int aOff = (wr * 64 + l16) * BK + pq;
  const int bOff = (wc * 64 + l16) * BK + pq;

  for (int k0 = 0; k0 < 1024; k0 += BK) {
    const unsigned kb = (unsigned)k0 * 2u;
    #pragma unroll
    for (int s = 0; s < 4; ++s) {
      gload_lds16(Abase + kb + offA[s], As + s * 2048 + wave * 512);
      gload_lds16(Bbase + kb + offB[s], Bs + s * 2048 + wave * 512);
    }
    __syncthreads();
    #pragma unroll
    for (int h = 0; h < 2; ++h) {
      const int hx = h * 32;
      bf16x8 af[4], bfr[4];
      #pragma unroll
      for (int i = 0; i < 4; ++i)
        af[i] = *(const bf16x8*)(As + ((aOff + i * 16 * BK) ^ hx));
      #pragma unroll
      for (int j = 0; j < 4; ++j)
        bfr[j] = *(const bf16x8*)(Bs + ((bOff + j * 16 * BK) ^ hx));
      #pragma unroll
      for (int i = 0; i < 4; ++i)
        #pragma unroll
        for (int j = 0; j < 4; ++j)
          acc[i][j] = __builtin_amdgcn_mfma_f32_16x16x32_bf16(af[i], bfr[j], acc[i][j], 0, 0, 0);
    }
    __syncthreads();
  }

  const int row0 = by * 128 + wr * 64 + quad * 4;
  const int col0 = bx * 128 + wc * 64 + l16;
  unsigned short* C = (bx < 8) ? Qb : Kb;
  const int col = (bx < 8) ? col0 : col0 - 1024;
  #pragma unroll
  for (int i = 0; i < 4; ++i)
    #pragma unroll
    for (int r = 0; r < 4; ++r) {
      const size_t rr = (size_t)(row0 + i * 16 + r) * 1024;
      #pragma unroll
      for (int j = 0; j < 4; ++j)
        C[rr + col + j * 16] = f2bf(acc[i][j][r]);
    }
}

// ---------- merged scores + V-GEMM (128x128, BK=64), 1056 blocks -----------
// Per-XCD chunks of 132 (lin&7 = XCD), positions alternate scores/V so both
// types are co-resident on every CU. scores: triangular unpack; V: A=Xbf,
// B=Wv; output transposed into Vt[b][e][s].
__global__ __launch_bounds__(256, 3)
void gemm_sv(const unsigned short* __restrict__ Qb,
             const unsigned short* __restrict__ Kb,
             const unsigned short* __restrict__ Xbf,
             const unsigned short* __restrict__ Wall,
             unsigned short* __restrict__ S,
             float* __restrict__ L,
             unsigned short* __restrict__ Vt)
{
  const int lin = blockIdx.x;          // 0..1055
  const int c = lin & 7;               // XCD chunk id
  const int pos = lin >> 3;            // 0..131 position within chunk
  const bool isV = (pos < 128) && (pos & 1);

  int by, bxr, bz = 0;
  const unsigned short *Ab, *Bb;
  if (!isV) {
    const int s_loc = (pos < 128) ? (pos >> 1) : (64 + (pos - 128));
    const int sidx = c * 68 + s_loc;           // 0..543
    bz = sidx / 136;
    const int t = sidx - bz * 136;
    int byy = (int)((sqrtf(8.f * t + 1.f) - 1.f) * 0.5f);
    while ((byy + 1) * (byy + 2) / 2 <= t) ++byy;
    while (byy * (byy + 1) / 2 > t) --byy;
    by = byy;
    bxr = t - byy * (byy + 1) / 2;
    Ab = Qb + (size_t)bz * 2097152;
    Bb = Kb + (size_t)bz * 2097152;
  } else {
    const int v = c * 64 + (pos >> 1);         // 0..511
    by = v >> 3;                               // 0..63 (global X row-tile)
    bxr = v & 7;                               // Wv col-tile
    Ab = Xbf;
    Bb = Wall + 2 * 1048576;
  }

  __shared__ __align__(16) unsigned short As2[128 * BK];
  __shared__ __align__(16) unsigned short Bs2[128 * BK];

  const int tid = threadIdx.x;
  const int wave = tid >> 6, lane = tid & 63;
  const int wr = wave >> 1, wc = wave & 1;
  const int quad = lane >> 4, l16 = lane & 15;

  const unsigned rsub = wave * 8 + (lane >> 3);
  const unsigned csb = (unsigned)(((lane & 7) ^ ((lane >> 3) & 7)) * 16);

  unsigned offA[4], offB[4];
  #pragma unroll
  for (int s = 0; s < 4; ++s) {
    offA[s] = ((unsigned)(by * 128 + s * 32 + rsub) * 1024u) * 2u + csb;
    offB[s] = ((unsigned)(bxr * 128 + s * 32 + rsub) * 1024u) * 2u + csb;
  }
  const char* Abase = (const char*)Ab;
  const char* Bbase = (const char*)Bb;

  f32x4 acc[4][4];
  #pragma unroll
  for (int i = 0; i < 4; ++i)
    #pragma unroll
    for (int j = 0; j < 4; ++j)
      acc[i][j] = (f32x4){0.f, 0.f, 0.f, 0.f};

  const int pq = (quad ^ (l16 & 7)) * 8;
  const int aOff = (wr * 64 + l16) * BK + pq;
  const int bOff = (wc * 64 + l16) * BK + pq;

  for (int k0 = 0; k0 < 1024; k0 += BK) {
    const unsigned kb = (unsigned)k0 * 2u;
    #pragma unroll
    for (int s = 0; s < 4; ++s) {
      gload_lds16(Abase + kb + offA[s], As2 + s * 2048 + wave * 512);
      gload_lds16(Bbase + kb + offB[s], Bs2 + s * 2048 + wave * 512);
    }
    __syncthreads();
    #pragma unroll
    for (int h = 0; h < 2; ++h) {
      const int hx = h * 32;
      bf16x8 af[4], bfr[4];
      #pragma unroll
      for (int i = 0; i < 4; ++i)
        af[i] = *(const bf16x8*)(As2 + ((aOff + i * 16 * BK) ^ hx));
      #pragma unroll
      for (int j = 0; j < 4; ++j)
        bfr[j] = *(const bf16x8*)(Bs2 + ((bOff + j * 16 * BK) ^ hx));
      #pragma unroll
      for (int i = 0; i < 4; ++i)
        #pragma unroll
        for (int j = 0; j < 4; ++j)
          acc[i][j] = __builtin_amdgcn_mfma_f32_16x16x32_bf16(af[i], bfr[j], acc[i][j], 0, 0, 0);
    }
    __syncthreads();
  }

  const int row0 = by * 128 + wr * 64 + quad * 4;
  if (!isV) {
    const int col0 = bxr * 128 + wc * 64 + l16;
    float* Lb = L + (size_t)bz * 2048;
    unsigned short* C = S + (size_t)bz * 4194304;
    #pragma unroll
    for (int i = 0; i < 4; ++i)
      #pragma unroll
      for (int r = 0; r < 4; ++r) {
        const int grow = row0 + i * 16 + r;
        float ps = 0.f;
        #pragma unroll
        for (int j = 0; j < 4; ++j) {
          const int gcol = col0 + j * 16;
          float e = (gcol <= grow) ? __expf(acc[i][j][r] * 0.03125f) : 0.f;
          acc[i][j][r] = e;
          ps += e;
        }
        #pragma unroll
        for (int m = 8; m > 0; m >>= 1)
          ps += __shfl_xor(ps, m);
        if (l16 == 0) atomicAdd(&Lb[grow], ps);
        const size_t rr = (size_t)grow * 2048;
        #pragma unroll
        for (int j = 0; j < 4; ++j)
          C[rr + col0 + j * 16] = f2bf(acc[i][j][r]);
      }
  } else {
    const int b = row0 >> 11;
    const int s0 = row0 & 2047;
    unsigned short* Vb = Vt + (size_t)b * 2097152;
    const int e0 = bxr * 128 + wc * 64 + l16;
    #pragma unroll
    for (int j = 0; j < 4; ++j) {
      const size_t ee = (size_t)(e0 + j * 16) * 2048;
      #pragma unroll
      for (int i = 0; i < 4; ++i) {
        ushort4 o;
        o.x = f2bf(acc[i][j][0]); o.y = f2bf(acc[i][j][1]);
        o.z = f2bf(acc[i][j][2]); o.w = f2bf(acc[i][j][3]);
        *(ushort4*)(Vb + ee + s0 + i * 16) = o;
      }
    }
  }
}

// ------------- PV (128x128, BK=64) with 1/L norm + split-K ------------------
// Out[b] = (P'[b] @ Vt[b]^T) / L; grid (8, 24, 4).
//   y < 16: split rows by = 8 + (y>>1), half = y&1; k-steps (by+1) each;
//           epilogue atomicAdd of pre-normalized partial (Out zeroed in cvt).
//   y >= 16: by = 23 - y (7..0, biggest-first); plain store.
// Critical path: 16 k-steps for every block (was 32 at by=15).
__global__ __launch_bounds__(256, 3)
void gemm_pv(const unsigned short* __restrict__ P,
             const unsigned short* __restrict__ Vt,
             float* __restrict__ Out,
             const float* __restrict__ L)
{
  const int bx = blockIdx.x, bz = blockIdx.z;
  const bool split = (blockIdx.y < 16);
  int by, kbeg, kend;
  if (split) {
    by = 8 + (blockIdx.y >> 1);
    const int half = blockIdx.y & 1;
    const int hlen = (by + 1) * 64;          // half-range in k-elements
    kbeg = half * hlen;
    kend = kbeg + hlen;
  } else {
    by = 23 - blockIdx.y;                    // 7..0
    kbeg = 0;
    kend = (by + 1) * 128;
  }

  __shared__ __align__(16) unsigned short As2[128 * BK];
  __shared__ __align__(16) unsigned short Bs2[128 * BK];

  const int tid = threadIdx.x;
  const int wave = tid >> 6, lane = tid & 63;
  const int wr = wave >> 1, wc = wave & 1;
  const int quad = lane >> 4, l16 = lane & 15;

  const unsigned rsub = wave * 8 + (lane >> 3);
  const unsigned csb = (unsigned)(((lane & 7) ^ ((lane >> 3) & 7)) * 16);

  unsigned offA[4], offB[4];
  #pragma unroll
  for (int s = 0; s < 4; ++s) {
    offA[s] = ((unsigned)(by * 128 + s * 32 + rsub) * 2048u) * 2u + csb;
    offB[s] = ((unsigned)(bx * 128 + s * 32 + rsub) * 2048u) * 2u + csb;
  }
  const char* Abase = (const char*)(P + (size_t)bz * 4194304);
  const char* Bbase = (const char*)(Vt + (size_t)bz * 2097152);

  f32x4 acc[4][4];
  #pragma unroll
  for (int i = 0; i < 4; ++i)
    #pragma unroll
    for (int j = 0; j < 4; ++j)
      acc[i][j] = (f32x4){0.f, 0.f, 0.f, 0.f};

  const int pq = (quad ^ (l16 & 7)) * 8;
  const int aOff = (wr * 64 + l16) * BK + pq;
  const int bOff = (wc * 64 + l16) * BK + pq;

  for (int k0 = kbeg; k0 < kend; k0 += BK) {
    const unsigned kb = (unsigned)k0 * 2u;
    #pragma unroll
    for (int s = 0; s < 4; ++s) {
      gload_lds16(Abase + kb + offA[s], As2 + s * 2048 + wave * 512);
      gload_lds16(Bbase + kb + offB[s], Bs2 + s * 2048 + wave * 512);
    }
    __syncthreads();
    #pragma unroll
    for (int h = 0; h < 2; ++h) {
      const int hx = h * 32;
      bf16x8 af[4], bfr[4];
      #pragma unroll
      for (int i = 0; i < 4; ++i)
        af[i] = *(const bf16x8*)(As2 + ((aOff + i * 16 * BK) ^ hx));
      #pragma unroll
      for (int j = 0; j < 4; ++j)
        bfr[j] = *(const bf16x8*)(Bs2 + ((bOff + j * 16 * BK) ^ hx));
      #pragma unroll
      for (int i = 0; i < 4; ++i)
        #pragma unroll
        for (int j = 0; j < 4; ++j)
          acc[i][j] = __builtin_amdgcn_mfma_f32_16x16x32_bf16(af[i], bfr[j], acc[i][j], 0, 0, 0);
    }
    __syncthreads();
  }

  const int row0 = by * 128 + wr * 64 + quad * 4;
  const int col0 = bx * 128 + wc * 64 + l16;
  float* C = Out + (size_t)bz * 2097152;
  const float* Lb = L + (size_t)bz * 2048;
  if (split) {
    #pragma unroll
    for (int i = 0; i < 4; ++i)
      #pragma unroll
      for (int r = 0; r < 4; ++r) {
        const int grow = row0 + i * 16 + r;
        const float inv = 1.0f / Lb[grow];
        const size_t rr = (size_t)grow * 1024;
        #pragma unroll
        for (int j = 0; j < 4; ++j)
          atomicAdd(&C[rr + col0 + j * 16], acc[i][j][r] * inv);
      }
  } else {
    #pragma unroll
    for (int i = 0; i < 4; ++i)
      #pragma unroll
      for (int r = 0; r < 4; ++r) {
        const int grow = row0 + i * 16 + r;
        const float inv = 1.0f / Lb[grow];
        const size_t rr = (size_t)grow * 1024;
        #pragma unroll
        for (int j = 0; j < 4; ++j)
          C[rr + col0 + j * 16] = acc[i][j][r] * inv;
      }
  }
}

// -------------------- launch --------------------
extern "C" void kernel_launch(void* const* d_in, const int* in_sizes, int n_in,
                              void* d_out, int out_size, void* d_ws, size_t ws_size,
                              hipStream_t stream) {
  const float* X  = (const float*)d_in[0];
  const float* Wq = (const float*)d_in[1];
  const float* Wk = (const float*)d_in[2];
  const float* Wv = (const float*)d_in[3];
  float* Out = (float*)d_out;

  char* ws = (char*)d_ws;
  unsigned short* Xbf  = (unsigned short*)(ws);              // [8192][1024]    16 MiB
  unsigned short* Wall = (unsigned short*)(ws + 16777216);   // [3072][1024]     6 MiB
  unsigned short* Qbf  = (unsigned short*)(ws + 23068672);   // [8192][1024]    16 MiB
  unsigned short* Kbf  = (unsigned short*)(ws + 39845888);   // [8192][1024]    16 MiB
  unsigned short* Vt   = (unsigned short*)(ws + 56623104);   // [4][1024][2048] 16 MiB
  unsigned short* Sbf  = (unsigned short*)(ws + 73400320);   // [4][2048][2048] 32 MiB
  float*          Lbuf = (float*)(ws + 106954752);           // [4][2048]       32 KiB

  cvt_all<<<12292, 256, 0, stream>>>(X, Wq, Wk, Wv, Xbf, Wall, Lbuf, Out);

  gemm_qkv<<<dim3(16, 64), 256, 0, stream>>>(Xbf, Wall, Qbf, Kbf);

  gemm_sv<<<1056, 256, 0, stream>>>(Qbf, Kbf, Xbf, Wall, Sbf, Lbuf, Vt);

  gemm_pv<<<dim3(8, 24, 4), 256, 0, stream>>>(Sbf, Vt, Out, Lbuf);
}

// Round 9
// 211.938 us; speedup vs baseline: 1.0728x; 1.0728x over previous
//
#include <hip/hip_runtime.h>
#include <cstdint>

// B=4, S=2048, D_IN=D_OUT=1024; softmax scale = 1/sqrt(1024) = 0.03125
// exp without max-subtraction is safe (|scores| ~< 3); L = rowsum via atomics;
// 1/L folded into PV epilogue.
//
// R9 = R4 revert (best measured, 217.0us) + one zero-cost tweak:
// pv biggest-kmax-first (by = 15 - blockIdx.y, LPT order).
// GEMM structure: 128x128 tile, BK=64, 8-chunk XOR LDS swizzle (0 conflicts
// measured), global_load_lds staging, T1 bijective XCD swizzle (qkv, scores).
// Session ledger: R2 256^2 8-phase = 84us qkv (1 blk/CU lockstep, reverted);
// R5 col-64 split = +7us (reverted); R7 sv-merge = neutral; R8 split-K pv =
// +9us (atomics + zeroing, reverted). Plateau {R4 217.0, R7 218.0}, noise
// +/-5-10us; per-block rate maxed at m97 ceiling (qkv 865 TF @ 6 rounds/CU),
// residual ~40us is harness reset + launch gaps.

typedef __attribute__((ext_vector_type(8))) __bf16 bf16x8;
typedef __attribute__((ext_vector_type(4))) float f32x4;

#define BK 64

__device__ __forceinline__ unsigned short f2bf(float f) {
  union { float f; unsigned u; } v; v.f = f;
  unsigned r = v.u + 0x7fffu + ((v.u >> 16) & 1u);  // RNE
  return (unsigned short)(r >> 16);
}

__device__ __forceinline__ void gload_lds16(const void* g, void* l) {
  __builtin_amdgcn_global_load_lds(
      (const __attribute__((address_space(1))) void*)g,
      (__attribute__((address_space(3))) void*)l, 16, 0, 0);
}

// ------------- fused fp32->bf16 conversion (X + weights) + L zero ----------
__global__ __launch_bounds__(256)
void cvt_all(const float* __restrict__ X, const float* __restrict__ Wq,
             const float* __restrict__ Wk, const float* __restrict__ Wv,
             unsigned short* __restrict__ Xbf, unsigned short* __restrict__ Wall,
             float* __restrict__ L) {
  const int bid = blockIdx.x;
  if (bid >= 11264) {  // 4 blocks zero L[4][2048]
    float4* p = (float4*)(L + (size_t)(bid - 11264) * 2048);
    p[threadIdx.x] = (float4){0.f, 0.f, 0.f, 0.f};
    p[threadIdx.x + 256] = (float4){0.f, 0.f, 0.f, 0.f};
    return;
  }
  const float* src;
  unsigned short* dst;
  int i;
  if (bid < 8192) {
    src = X; dst = Xbf; i = bid * 256 + threadIdx.x;
  } else {
    const int m = bid - 8192;
    const int sel = m >> 10;
    src = (sel == 0) ? Wq : (sel == 1) ? Wk : Wv;
    dst = Wall + (size_t)sel * 1048576;
    i = (m & 1023) * 256 + threadIdx.x;
  }
  float4 v = ((const float4*)src)[i];
  ushort4 o;
  o.x = f2bf(v.x); o.y = f2bf(v.y); o.z = f2bf(v.z); o.w = f2bf(v.w);
  ((ushort4*)dst)[i] = o;
}

// -------------------- fused QKV GEMM (128x128, BK=64) --------------------
// A = Xbf [8192][1024], B = Wall [3072][1024]
// grid (24, 64): bx<8 -> Q; bx<16 -> K; else V transposed into Vt[b][e][s].
__global__ __launch_bounds__(256, 3)
void gemm_qkv(const unsigned short* __restrict__ A,
              const unsigned short* __restrict__ Bm,
              unsigned short* __restrict__ Qb,
              unsigned short* __restrict__ Kb,
              unsigned short* __restrict__ Vt)
{
  // T1: bijective XCD swizzle (1536 % 8 == 0). Dispatch order is x-fastest,
  // so lin%8 = XCD id; give each XCD 192 consecutive tiles = 8 full by-rows
  // (A-panel working set 8*256KB = 2MB < 4MB XCD L2).
  const int lin = blockIdx.y * 24 + blockIdx.x;
  const int swz = (lin & 7) * 192 + (lin >> 3);
  const int bx = swz % 24, by = swz / 24;

  __shared__ __align__(16) unsigned short As[128 * BK];  // 16 KB
  __shared__ __align__(16) unsigned short Bs[128 * BK];  // 16 KB

  const int tid = threadIdx.x;
  const int wave = tid >> 6, lane = tid & 63;
  const int wr = wave >> 1, wc = wave & 1;
  const int quad = lane >> 4, l16 = lane & 15;

  const unsigned rsub = wave * 8 + (lane >> 3);
  const unsigned csb = (unsigned)(((lane & 7) ^ ((lane >> 3) & 7)) * 16);  // byte off in row

  // per-lane 32-bit byte offsets; uniform bases stay in SGPRs
  unsigned offA[4], offB[4];
  #pragma unroll
  for (int s = 0; s < 4; ++s) {
    offA[s] = ((unsigned)(by * 128 + s * 32 + rsub) * 1024u) * 2u + csb;
    offB[s] = ((unsigned)(bx * 128 + s * 32 + rsub) * 1024u) * 2u + csb;
  }
  const char* Abase = (const char*)A;
  const char* Bbase = (const char*)Bm;

  f32x4 acc[4][4];
  #pragma unroll
  for (int i = 0; i < 4; ++i)
    #pragma unroll
    for (int j = 0; j < 4; ++j)
      acc[i][j] = (f32x4){0.f, 0.f, 0.f, 0.f};

  const int pq = (quad ^ (l16 & 7)) * 8;
  const int aOff = (wr * 64 + l16) * BK + pq;
  const int bOff = (wc * 64 + l16) * BK + pq;

  for (int k0 = 0; k0 < 1024; k0 += BK) {
    const unsigned kb = (unsigned)k0 * 2u;
    #pragma unroll
    for (int s = 0; s < 4; ++s) {
      gload_lds16(Abase + kb + offA[s], As + s * 2048 + wave * 512);
      gload_lds16(Bbase + kb + offB[s], Bs + s * 2048 + wave * 512);
    }
    __syncthreads();
    #pragma unroll
    for (int h = 0; h < 2; ++h) {
      const int hx = h * 32;
      bf16x8 af[4], bfr[4];
      #pragma unroll
      for (int i = 0; i < 4; ++i)
        af[i] = *(const bf16x8*)(As + ((aOff + i * 16 * BK) ^ hx));
      #pragma unroll
      for (int j = 0; j < 4; ++j)
        bfr[j] = *(const bf16x8*)(Bs + ((bOff + j * 16 * BK) ^ hx));
      #pragma unroll
      for (int i = 0; i < 4; ++i)
        #pragma unroll
        for (int j = 0; j < 4; ++j)
          acc[i][j] = __builtin_amdgcn_mfma_f32_16x16x32_bf16(af[i], bfr[j], acc[i][j], 0, 0, 0);
    }
    __syncthreads();
  }

  const int row0 = by * 128 + wr * 64 + quad * 4;
  const int col0 = bx * 128 + wc * 64 + l16;
  if (bx < 16) {
    unsigned short* C = (bx < 8) ? Qb : Kb;
    const int col = (bx < 8) ? col0 : col0 - 1024;
    #pragma unroll
    for (int i = 0; i < 4; ++i)
      #pragma unroll
      for (int r = 0; r < 4; ++r) {
        const size_t rr = (size_t)(row0 + i * 16 + r) * 1024;
        #pragma unroll
        for (int j = 0; j < 4; ++j)
          C[rr + col + j * 16] = f2bf(acc[i][j][r]);
      }
  } else {
    const int b = row0 >> 11;
    const int s0 = row0 & 2047;
    unsigned short* Vb = Vt + (size_t)b * 2097152;
    #pragma unroll
    for (int j = 0; j < 4; ++j) {
      const size_t ee = (size_t)(col0 - 2048 + j * 16) * 2048;
      #pragma unroll
      for (int i = 0; i < 4; ++i) {
        ushort4 o;
        o.x = f2bf(acc[i][j][0]); o.y = f2bf(acc[i][j][1]);
        o.z = f2bf(acc[i][j][2]); o.w = f2bf(acc[i][j][3]);
        *(ushort4*)(Vb + ee + s0 + i * 16) = o;
      }
    }
  }
}

// -------------------- scores (128x128, BK=64) + exp + rowsum ----------------
// S'[b] = exp(scale*Q@K^T) causal-masked, bf16; L[b][q] += partial rowsums.
// Triangular-packed grid.x (136 tiles), z = batch.
__global__ __launch_bounds__(256, 3)
void gemm_scores(const unsigned short* __restrict__ Q,
                 const unsigned short* __restrict__ Km,
                 unsigned short* __restrict__ S,
                 float* __restrict__ L)
{
  // T1: bijective XCD swizzle over 136 = 8*17 triangular tiles; consecutive
  // t' share by -> Q-panel L2 reuse within an XCD.
  const int t0i = blockIdx.x;
  const int t = (t0i & 7) * 17 + (t0i >> 3);
  const int bz = blockIdx.z;
  int by = (int)((sqrtf(8.f * t + 1.f) - 1.f) * 0.5f);
  while ((by + 1) * (by + 2) / 2 <= t) ++by;
  while (by * (by + 1) / 2 > t) --by;
  const int bx = t - by * (by + 1) / 2;

  __shared__ __align__(16) unsigned short As2[128 * BK];
  __shared__ __align__(16) unsigned short Bs2[128 * BK];

  const int tid = threadIdx.x;
  const int wave = tid >> 6, lane = tid & 63;
  const int wr = wave >> 1, wc = wave & 1;
  const int quad = lane >> 4, l16 = lane & 15;

  const unsigned rsub = wave * 8 + (lane >> 3);
  const unsigned csb = (unsigned)(((lane & 7) ^ ((lane >> 3) & 7)) * 16);

  unsigned offA[4], offB[4];
  #pragma unroll
  for (int s = 0; s < 4; ++s) {
    offA[s] = ((unsigned)(by * 128 + s * 32 + rsub) * 1024u) * 2u + csb;
    offB[s] = ((unsigned)(bx * 128 + s * 32 + rsub) * 1024u) * 2u + csb;
  }
  const char* Abase = (const char*)(Q + (size_t)bz * 2097152);
  const char* Bbase = (const char*)(Km + (size_t)bz * 2097152);

  f32x4 acc[4][4];
  #pragma unroll
  for (int i = 0; i < 4; ++i)
    #pragma unroll
    for (int j = 0; j < 4; ++j)
      acc[i][j] = (f32x4){0.f, 0.f, 0.f, 0.f};

  const int pq = (quad ^ (l16 & 7)) * 8;
  const int aOff = (wr * 64 + l16) * BK + pq;
  const int bOff = (wc * 64 + l16) * BK + pq;

  for (int k0 = 0; k0 < 1024; k0 += BK) {
    const unsigned kb = (unsigned)k0 * 2u;
    #pragma unroll
    for (int s = 0; s < 4; ++s) {
      gload_lds16(Abase + kb + offA[s], As2 + s * 2048 + wave * 512);
      gload_lds16(Bbase + kb + offB[s], Bs2 + s * 2048 + wave * 512);
    }
    __syncthreads();
    #pragma unroll
    for (int h = 0; h < 2; ++h) {
      const int hx = h * 32;
      bf16x8 af[4], bfr[4];
      #pragma unroll
      for (int i = 0; i < 4; ++i)
        af[i] = *(const bf16x8*)(As2 + ((aOff + i * 16 * BK) ^ hx));
      #pragma unroll
      for (int j = 0; j < 4; ++j)
        bfr[j] = *(const bf16x8*)(Bs2 + ((bOff + j * 16 * BK) ^ hx));
      #pragma unroll
      for (int i = 0; i < 4; ++i)
        #pragma unroll
        for (int j = 0; j < 4; ++j)
          acc[i][j] = __builtin_amdgcn_mfma_f32_16x16x32_bf16(af[i], bfr[j], acc[i][j], 0, 0, 0);
    }
    __syncthreads();
  }

  const int row0 = by * 128 + wr * 64 + quad * 4;
  const int col0 = bx * 128 + wc * 64 + l16;
  float* Lb = L + (size_t)bz * 2048;
  unsigned short* C = S + (size_t)bz * 4194304;

  #pragma unroll
  for (int i = 0; i < 4; ++i)
    #pragma unroll
    for (int r = 0; r < 4; ++r) {
      const int grow = row0 + i * 16 + r;
      float ps = 0.f;
      #pragma unroll
      for (int j = 0; j < 4; ++j) {
        const int gcol = col0 + j * 16;
        float e = (gcol <= grow) ? __expf(acc[i][j][r] * 0.03125f) : 0.f;
        acc[i][j][r] = e;
        ps += e;
      }
      #pragma unroll
      for (int m = 8; m > 0; m >>= 1)
        ps += __shfl_xor(ps, m);
      if (l16 == 0) atomicAdd(&Lb[grow], ps);
      const size_t rr = (size_t)grow * 2048;
      #pragma unroll
      for (int j = 0; j < 4; ++j)
        C[rr + col0 + j * 16] = f2bf(acc[i][j][r]);
    }
}

// -------------------- PV (128x128, BK=64) with 1/L normalization ------------
// Out[b] = (P'[b] @ Vt[b]^T) / L; grid (8, 16, 4); by = 15 - blockIdx.y
// (biggest kmax first, LPT order); kmax = (by+1)*128.
__global__ __launch_bounds__(256, 3)
void gemm_pv(const unsigned short* __restrict__ P,
             const unsigned short* __restrict__ Vt,
             float* __restrict__ Out,
             const float* __restrict__ L)
{
  const int bx = blockIdx.x, by = 15 - blockIdx.y, bz = blockIdx.z;

  __shared__ __align__(16) unsigned short As2[128 * BK];
  __shared__ __align__(16) unsigned short Bs2[128 * BK];

  const int tid = threadIdx.x;
  const int wave = tid >> 6, lane = tid & 63;
  const int wr = wave >> 1, wc = wave & 1;
  const int quad = lane >> 4, l16 = lane & 15;

  const unsigned rsub = wave * 8 + (lane >> 3);
  const unsigned csb = (unsigned)(((lane & 7) ^ ((lane >> 3) & 7)) * 16);

  unsigned offA[4], offB[4];
  #pragma unroll
  for (int s = 0; s < 4; ++s) {
    offA[s] = ((unsigned)(by * 128 + s * 32 + rsub) * 2048u) * 2u + csb;
    offB[s] = ((unsigned)(bx * 128 + s * 32 + rsub) * 2048u) * 2u + csb;
  }
  const char* Abase = (const char*)(P + (size_t)bz * 4194304);
  const char* Bbase = (const char*)(Vt + (size_t)bz * 2097152);

  f32x4 acc[4][4];
  #pragma unroll
  for (int i = 0; i < 4; ++i)
    #pragma unroll
    for (int j = 0; j < 4; ++j)
      acc[i][j] = (f32x4){0.f, 0.f, 0.f, 0.f};

  const int kmax = (by + 1) * 128;  // causal truncation, multiple of BK

  const int pq = (quad ^ (l16 & 7)) * 8;
  const int aOff = (wr * 64 + l16) * BK + pq;
  const int bOff = (wc * 64 + l16) * BK + pq;

  for (int k0 = 0; k0 < kmax; k0 += BK) {
    const unsigned kb = (unsigned)k0 * 2u;
    #pragma unroll
    for (int s = 0; s < 4; ++s) {
      gload_lds16(Abase + kb + offA[s], As2 + s * 2048 + wave * 512);
      gload_lds16(Bbase + kb + offB[s], Bs2 + s * 2048 + wave * 512);
    }
    __syncthreads();
    #pragma unroll
    for (int h = 0; h < 2; ++h) {
      const int hx = h * 32;
      bf16x8 af[4], bfr[4];
      #pragma unroll
      for (int i = 0; i < 4; ++i)
        af[i] = *(const bf16x8*)(As2 + ((aOff + i * 16 * BK) ^ hx));
      #pragma unroll
      for (int j = 0; j < 4; ++j)
        bfr[j] = *(const bf16x8*)(Bs2 + ((bOff + j * 16 * BK) ^ hx));
      #pragma unroll
      for (int i = 0; i < 4; ++i)
        #pragma unroll
        for (int j = 0; j < 4; ++j)
          acc[i][j] = __builtin_amdgcn_mfma_f32_16x16x32_bf16(af[i], bfr[j], acc[i][j], 0, 0, 0);
    }
    __syncthreads();
  }

  const int row0 = by * 128 + wr * 64 + quad * 4;
  const int col0 = bx * 128 + wc * 64 + l16;
  float* C = Out + (size_t)bz * 2097152;
  const float* Lb = L + (size_t)bz * 2048;
  #pragma unroll
  for (int i = 0; i < 4; ++i)
    #pragma unroll
    for (int r = 0; r < 4; ++r) {
      const int grow = row0 + i * 16 + r;
      const float inv = 1.0f / Lb[grow];
      const size_t rr = (size_t)grow * 1024;
      #pragma unroll
      for (int j = 0; j < 4; ++j)
        C[rr + col0 + j * 16] = acc[i][j][r] * inv;
    }
}

// -------------------- launch --------------------
extern "C" void kernel_launch(void* const* d_in, const int* in_sizes, int n_in,
                              void* d_out, int out_size, void* d_ws, size_t ws_size,
                              hipStream_t stream) {
  const float* X  = (const float*)d_in[0];
  const float* Wq = (const float*)d_in[1];
  const float* Wk = (const float*)d_in[2];
  const float* Wv = (const float*)d_in[3];
  float* Out = (float*)d_out;

  char* ws = (char*)d_ws;
  unsigned short* Xbf  = (unsigned short*)(ws);              // [8192][1024]    16 MiB
  unsigned short* Wall = (unsigned short*)(ws + 16777216);   // [3072][1024]     6 MiB
  unsigned short* Qbf  = (unsigned short*)(ws + 23068672);   // [8192][1024]    16 MiB
  unsigned short* Kbf  = (unsigned short*)(ws + 39845888);   // [8192][1024]    16 MiB
  unsigned short* Vt   = (unsigned short*)(ws + 56623104);   // [4][1024][2048] 16 MiB
  unsigned short* Sbf  = (unsigned short*)(ws + 73400320);   // [4][2048][2048] 32 MiB
  float*          Lbuf = (float*)(ws + 106954752);           // [4][2048]       32 KiB

  cvt_all<<<11268, 256, 0, stream>>>(X, Wq, Wk, Wv, Xbf, Wall, Lbuf);

  gemm_qkv<<<dim3(24, 64), 256, 0, stream>>>(Xbf, Wall, Qbf, Kbf, Vt);

  gemm_scores<<<dim3(136, 1, 4), 256, 0, stream>>>(Qbf, Kbf, Sbf, Lbuf);

  gemm_pv<<<dim3(8, 16, 4), 256, 0, stream>>>(Sbf, Vt, Out, Lbuf);
}